// Round 7
// baseline (1952.720 us; speedup 1.0000x reference)
//
#include <hip/hip_runtime.h>
#include <cmath>

constexpr int  Bn  = 32, Tn = 512, NIn = 128, Hn = 1024;
constexpr long long TH  = (long long)Tn * Hn;    // 524288
constexpr long long BTH = (long long)Bn * TH;    // 16777216
constexpr float DTc  = 0.042f;
constexpr float UDEC = 1.0f - 1.0f * 1.0f * DTc; // R*C*dt leak
constexpr float HARM = 512.0f;                   // n_hid * p
constexpr float SPIK = 512.0f;                   // n_hid - harmonic

// Per-(b-group, writer-block) step tags, one 64B cacheline each.
// Up to 16 b-groups x 32 writers. Writer publishes tag=t+1 after hy drains.
__device__ unsigned g_tag[16 * 32 * 16];

__global__ void init_tag() {
    int i = threadIdx.x;             // 512 threads, one line each
    __hip_atomic_store(&g_tag[i * 16], 0u,
                       __ATOMIC_RELAXED, __HIP_MEMORY_SCOPE_AGENT);
}

// ---------------------------------------------------------------------------
// pre[row, col] = x[row, :] @ x2h[:, col] + bias[col]  (unchanged, verified)
// ---------------------------------------------------------------------------
__global__ __launch_bounds__(256) void pre_gemm(const float* __restrict__ x,
                                                const float* __restrict__ x2h,
                                                const float* __restrict__ bias,
                                                float* __restrict__ pre) {
    __shared__ float xs[64 * 128];   // [row][k]
    __shared__ float ws[128 * 64];   // [k][col]
    const int tid = threadIdx.x;
    const int rb  = blockIdx.y * 64;
    const int cb  = blockIdx.x * 64;

#pragma unroll
    for (int i = 0; i < 8; ++i) {
        int idx = i * 1024 + tid * 4;
        int r = idx >> 7, k = idx & 127;
        *(float4*)(&xs[r * 128 + k]) =
            *(const float4*)(&x[(long long)(rb + r) * NIn + k]);
    }
#pragma unroll
    for (int i = 0; i < 8; ++i) {
        int idx = i * 1024 + tid * 4;
        int k = idx >> 6, c = idx & 63;
        *(float4*)(&ws[k * 64 + c]) =
            *(const float4*)(&x2h[(long long)k * Hn + cb + c]);
    }
    __syncthreads();

    const int tx = tid & 15, ty = tid >> 4;
    const int r0 = ty * 4, c0 = tx * 4;
    float acc[4][4] = {};
#pragma unroll 4
    for (int k = 0; k < 128; ++k) {
        float4 bv = *(const float4*)(&ws[k * 64 + c0]);
        float a0 = xs[(r0 + 0) * 128 + k];
        float a1 = xs[(r0 + 1) * 128 + k];
        float a2 = xs[(r0 + 2) * 128 + k];
        float a3 = xs[(r0 + 3) * 128 + k];
        acc[0][0] += a0 * bv.x; acc[0][1] += a0 * bv.y; acc[0][2] += a0 * bv.z; acc[0][3] += a0 * bv.w;
        acc[1][0] += a1 * bv.x; acc[1][1] += a1 * bv.y; acc[1][2] += a1 * bv.z; acc[1][3] += a1 * bv.w;
        acc[2][0] += a2 * bv.x; acc[2][1] += a2 * bv.y; acc[2][2] += a2 * bv.z; acc[2][3] += a2 * bv.w;
        acc[3][0] += a3 * bv.x; acc[3][1] += a3 * bv.y; acc[3][2] += a3 * bv.z; acc[3][3] += a3 * bv.w;
    }
    float4 bb = *(const float4*)(&bias[cb + c0]);
#pragma unroll
    for (int i = 0; i < 4; ++i) {
        float4 o;
        o.x = acc[i][0] + bb.x; o.y = acc[i][1] + bb.y;
        o.z = acc[i][2] + bb.z; o.w = acc[i][3] + bb.w;
        *(float4*)(&pre[(long long)(rb + r0 + i) * Hn + cb + c0]) = o;
    }
}

// ---------------------------------------------------------------------------
// R8 primary: 512 blocks = 16 b-groups x 32 h-groups, 2 blocks/CU.
// LDS cut to 41120 B (h2h staged through an 8-col chunk buffer) so the
// cooperative-launch occupancy check cannot round us down to 1 block/CU.
// ---------------------------------------------------------------------------
__global__ __launch_bounds__(256, 2) void ron_loop2(const float* __restrict__ h2h,
                                                    const float* __restrict__ gam,
                                                    const float* __restrict__ eps,
                                                    float* __restrict__ out) {
    extern __shared__ float sm[];
    float* hyl  = sm;                // 2 * 1028 floats (staging)
    float* wtb  = sm + 2 * 1028;     // 8 * 1028 floats (W chunk buf, then scratch)
    float* part = wtb;               // alias: 64 outputs * 33 floats (2112)

    const int tid = threadIdx.x;
    const int bx  = blockIdx.x;
    const int bg  = ((bx & 7) << 1) | (bx >> 8);  // 0..15, XCD-local pairs
    const int hg  = (bx >> 3) & 31;               // 0..31
    const int c0  = hg * 32;
    const int b0  = bg * 2;
    unsigned* mytag   = &g_tag[(bg * 32 + hg) * 16];
    unsigned* tagbase = &g_tag[bg * 32 * 16];

    float* hy_o = out;
    float* hz_o = out + BTH;
    float* u_o  = out + 2 * BTH;     // holds pre until overwritten by u
    float* sp_o = out + 3 * BTH;

    const int ks   = tid & 31;       // K-split lane: float4 index ks + 32*m
    const int tile = tid >> 5;       // 0..7: cols tile*4 .. tile*4+3

    // Stage h2h in four 8-col chunks; owning tiles copy W to registers.
    float4 W[4][8];
#pragma unroll
    for (int ch = 0; ch < 4; ++ch) {
        for (int idx = tid; idx < 8 * 1024; idx += 256) {
            int cc2 = idx & 7, k = idx >> 3;
            wtb[cc2 * 1028 + k] = h2h[(long long)k * Hn + c0 + ch * 8 + cc2];
        }
        __syncthreads();
        if ((tile >> 1) == ch) {
#pragma unroll
            for (int j = 0; j < 4; ++j)
#pragma unroll
                for (int m = 0; m < 8; ++m)
                    W[j][m] = *(const float4*)(wtb + ((tile & 1) * 4 + j) * 1028
                                               + (ks + 32 * m) * 4);
        }
        __syncthreads();   // copy reads drained before restage / part writes
    }
    // wtb region is dead from here on; reused as 'part' from t=1.

    const float* hp0 = hyl + ks * 4;              // batch row 0
    const float* hp1 = hp0 + 1028;                // batch row 1
    float* pw = part + (tile * 4) * 33 + ks;      // + (bi*32 + j)*33

    // ---- update-phase identity (threads 0..63 own one (b,h) output) ----
    const int r  = tid & 63;
    const int cc = r & 31;
    const int bb = r >> 5;
    const int b  = b0 + bb;
    const int h  = c0 + cc;
    const float g = gam[h];
    const float e = eps[h];
    float hy = 0.0f, hz = 0.0f, u = 0.0f;

#define D4(dst, hv, wv)                                         \
    dst = fmaf(hv.x, wv.x, dst); dst = fmaf(hv.y, wv.y, dst);   \
    dst = fmaf(hv.z, wv.z, dst); dst = fmaf(hv.w, wv.w, dst)

    for (int t = 0; t < Tn; ++t) {
        float pre_v = 0.0f;
        if (tid < 64)
            pre_v = u_o[(long long)b * TH + (long long)t * Hn + h];

        float acc = 0.0f;
        if (t > 0) {
            // ---- stage previous hy rows (2 x 1024): 8 loads in flight ----
            const long long base = (long long)b0 * TH + (long long)(t - 1) * Hn + tid;
            float v[8];
#pragma unroll
            for (int i = 0; i < 8; ++i) {
                v[i] = __hip_atomic_load(
                    &hy_o[base + (long long)(i >> 2) * TH + (i & 3) * 256],
                    __ATOMIC_RELAXED, __HIP_MEMORY_SCOPE_AGENT);
            }
#pragma unroll
            for (int i = 0; i < 8; ++i)
                hyl[(i >> 2) * 1028 + (i & 3) * 256 + tid] = v[i];
            __syncthreads();

            // ---- register-tiled dot: 2 batches x 4 cols, K=32 chunk ----
            float a00 = 0.f, a01 = 0.f, a02 = 0.f, a03 = 0.f;
            float a10 = 0.f, a11 = 0.f, a12 = 0.f, a13 = 0.f;
#pragma unroll
            for (int m = 0; m < 8; ++m) {
                const int o4 = m * 128;
                float4 h0 = *(const float4*)(hp0 + o4);
                float4 h1 = *(const float4*)(hp1 + o4);
                D4(a00, h0, W[0][m]); D4(a01, h0, W[1][m]);
                D4(a02, h0, W[2][m]); D4(a03, h0, W[3][m]);
                D4(a10, h1, W[0][m]); D4(a11, h1, W[1][m]);
                D4(a12, h1, W[2][m]); D4(a13, h1, W[3][m]);
            }

            pw[(0 * 32 + 0) * 33] = a00; pw[(0 * 32 + 1) * 33] = a01;
            pw[(0 * 32 + 2) * 33] = a02; pw[(0 * 32 + 3) * 33] = a03;
            pw[(1 * 32 + 0) * 33] = a10; pw[(1 * 32 + 1) * 33] = a11;
            pw[(1 * 32 + 2) * 33] = a12; pw[(1 * 32 + 3) * 33] = a13;
            __syncthreads();

            if (tid < 64) {
                const float* pr = part + r * 33;
                float s0 = 0.f, s1 = 0.f, s2 = 0.f, s3 = 0.f;
#pragma unroll
                for (int k = 0; k < 32; k += 4) {
                    s0 += pr[k + 0]; s1 += pr[k + 1];
                    s2 += pr[k + 2]; s3 += pr[k + 3];
                }
                acc = (s0 + s1) + (s2 + s3);
            }
        }

        float spike = 0.0f;
        long long o = 0;
        if (tid < 64) {
            spike = (u > 0.5f) ? 1.0f : 0.0f;
            u = (spike == 1.0f) ? 0.0f : u;
            u = u * UDEC;
            float drive = tanhf(acc + pre_v);
            hz = hz + DTc * (drive - g * hy - (e * (hz * HARM) + u * SPIK));
            hy = hy + DTc * hz;
            o = (long long)b * TH + (long long)t * Hn + h;
            __hip_atomic_store(&hy_o[o], hy,
                               __ATOMIC_RELAXED, __HIP_MEMORY_SCOPE_AGENT);
        }

        if (t < Tn - 1) {
            __syncthreads();   // drains vmcnt -> hy stores at coherent point
            if (tid == 0)
                __hip_atomic_store(mytag, (unsigned)(t + 1),
                                   __ATOMIC_RELAXED, __HIP_MEMORY_SCOPE_AGENT);
        }

        if (tid < 64) {        // off the publish critical path
            hz_o[o] = hz;
            u_o[o]  = u;
            sp_o[o] = spike;
        }

        if (t < Tn - 1) {
            if (tid < 64) {
                const unsigned target = (unsigned)(t + 1);
                const int idx = tid & 31;
                for (;;) {
                    unsigned v = __hip_atomic_load(&tagbase[idx * 16],
                                                   __ATOMIC_RELAXED,
                                                   __HIP_MEMORY_SCOPE_AGENT);
                    if (__ballot(v < target) == 0ull) break;
                    __builtin_amdgcn_s_sleep(1);
                }
            }
            __syncthreads();
        }
    }
#undef D4
}

// ---------------------------------------------------------------------------
// R8 fallback: the verified R6 kernel (256 blocks = 8 b-groups x 32 h-groups,
// 1 block/CU, 1716 us). Launched only if the 512-block path is rejected.
// ---------------------------------------------------------------------------
__global__ __launch_bounds__(256, 1) void ron_loop4(const float* __restrict__ h2h,
                                                    const float* __restrict__ gam,
                                                    const float* __restrict__ eps,
                                                    float* __restrict__ out) {
    extern __shared__ float sm[];
    float* hyl  = sm;                // 4 * 1028 floats (staging)
    float* wt   = sm + 4 * 1028;     // 32 * 1028 floats (weights, then scratch)
    float* part = wt;                // alias: 128 outputs * 33 floats

    const int tid = threadIdx.x;
    const int bx  = blockIdx.x;
    const int bg  = bx & 7;          // XCD id under round-robin dispatch
    const int hg  = bx >> 3;         // 32 h-groups
    const int c0  = hg * 32;
    const int b0  = bg * 4;
    unsigned* mytag   = &g_tag[(bg * 32 + hg) * 16];
    unsigned* tagbase = &g_tag[bg * 32 * 16];

    float* hy_o = out;
    float* hz_o = out + BTH;
    float* u_o  = out + 2 * BTH;
    float* sp_o = out + 3 * BTH;

    for (int idx = tid; idx < 32 * 1024; idx += 256) {
        int cc2 = idx & 31, k = idx >> 5;
        wt[cc2 * 1028 + k] = h2h[(long long)k * Hn + c0 + cc2];
    }
    __syncthreads();

    const int ks   = tid & 31;
    const int tile = tid >> 5;

    float4 W[4][8];
#pragma unroll
    for (int j = 0; j < 4; ++j)
#pragma unroll
        for (int m = 0; m < 8; ++m)
            W[j][m] = *(const float4*)(wt + (tile * 4 + j) * 1028 + (ks + 32 * m) * 4);

    const float* hp0 = hyl + ks * 4;
    const float* hp1 = hp0 + 1028;
    const float* hp2 = hp0 + 2 * 1028;
    const float* hp3 = hp0 + 3 * 1028;
    float* pw = part + (tile * 4) * 33 + ks;

    const int r  = tid & 127;
    const int cc = r & 31;
    const int bb = r >> 5;
    const int b  = b0 + bb;
    const int h  = c0 + cc;
    const float g = gam[h];
    const float e = eps[h];
    float hy = 0.0f, hz = 0.0f, u = 0.0f;

#define D4(dst, hv, wv)                                         \
    dst = fmaf(hv.x, wv.x, dst); dst = fmaf(hv.y, wv.y, dst);   \
    dst = fmaf(hv.z, wv.z, dst); dst = fmaf(hv.w, wv.w, dst)

    for (int t = 0; t < Tn; ++t) {
        float pre_v = 0.0f;
        if (tid < 128)
            pre_v = u_o[(long long)b * TH + (long long)t * Hn + h];

        float acc = 0.0f;
        if (t > 0) {
            const long long base = (long long)b0 * TH + (long long)(t - 1) * Hn + tid;
            float v[16];
#pragma unroll
            for (int i = 0; i < 16; ++i) {
                v[i] = __hip_atomic_load(
                    &hy_o[base + (long long)(i >> 2) * TH + (i & 3) * 256],
                    __ATOMIC_RELAXED, __HIP_MEMORY_SCOPE_AGENT);
            }
#pragma unroll
            for (int i = 0; i < 16; ++i)
                hyl[(i >> 2) * 1028 + (i & 3) * 256 + tid] = v[i];
            __syncthreads();

            float a00 = 0.f, a01 = 0.f, a02 = 0.f, a03 = 0.f;
            float a10 = 0.f, a11 = 0.f, a12 = 0.f, a13 = 0.f;
            float a20 = 0.f, a21 = 0.f, a22 = 0.f, a23 = 0.f;
            float a30 = 0.f, a31 = 0.f, a32 = 0.f, a33 = 0.f;
#pragma unroll
            for (int m = 0; m < 8; ++m) {
                const int o4 = m * 128;
                float4 h0 = *(const float4*)(hp0 + o4);
                float4 h1 = *(const float4*)(hp1 + o4);
                float4 h2 = *(const float4*)(hp2 + o4);
                float4 h3 = *(const float4*)(hp3 + o4);
                D4(a00, h0, W[0][m]); D4(a01, h0, W[1][m]); D4(a02, h0, W[2][m]); D4(a03, h0, W[3][m]);
                D4(a10, h1, W[0][m]); D4(a11, h1, W[1][m]); D4(a12, h1, W[2][m]); D4(a13, h1, W[3][m]);
                D4(a20, h2, W[0][m]); D4(a21, h2, W[1][m]); D4(a22, h2, W[2][m]); D4(a23, h2, W[3][m]);
                D4(a30, h3, W[0][m]); D4(a31, h3, W[1][m]); D4(a32, h3, W[2][m]); D4(a33, h3, W[3][m]);
            }

            pw[(0 * 32 + 0) * 33] = a00; pw[(0 * 32 + 1) * 33] = a01;
            pw[(0 * 32 + 2) * 33] = a02; pw[(0 * 32 + 3) * 33] = a03;
            pw[(1 * 32 + 0) * 33] = a10; pw[(1 * 32 + 1) * 33] = a11;
            pw[(1 * 32 + 2) * 33] = a12; pw[(1 * 32 + 3) * 33] = a13;
            pw[(2 * 32 + 0) * 33] = a20; pw[(2 * 32 + 1) * 33] = a21;
            pw[(2 * 32 + 2) * 33] = a22; pw[(2 * 32 + 3) * 33] = a23;
            pw[(3 * 32 + 0) * 33] = a30; pw[(3 * 32 + 1) * 33] = a31;
            pw[(3 * 32 + 2) * 33] = a32; pw[(3 * 32 + 3) * 33] = a33;
            __syncthreads();

            if (tid < 128) {
                const float* pr = part + r * 33;
                float s0 = 0.f, s1 = 0.f, s2 = 0.f, s3 = 0.f;
#pragma unroll
                for (int k = 0; k < 32; k += 4) {
                    s0 += pr[k + 0]; s1 += pr[k + 1];
                    s2 += pr[k + 2]; s3 += pr[k + 3];
                }
                acc = (s0 + s1) + (s2 + s3);
            }
        }

        float spike = 0.0f;
        long long o = 0;
        if (tid < 128) {
            spike = (u > 0.5f) ? 1.0f : 0.0f;
            u = (spike == 1.0f) ? 0.0f : u;
            u = u * UDEC;
            float drive = tanhf(acc + pre_v);
            hz = hz + DTc * (drive - g * hy - (e * (hz * HARM) + u * SPIK));
            hy = hy + DTc * hz;
            o = (long long)b * TH + (long long)t * Hn + h;
            __hip_atomic_store(&hy_o[o], hy,
                               __ATOMIC_RELAXED, __HIP_MEMORY_SCOPE_AGENT);
        }

        if (t < Tn - 1) {
            __syncthreads();
            if (tid == 0)
                __hip_atomic_store(mytag, (unsigned)(t + 1),
                                   __ATOMIC_RELAXED, __HIP_MEMORY_SCOPE_AGENT);
        }

        if (tid < 128) {
            hz_o[o] = hz;
            u_o[o]  = u;
            sp_o[o] = spike;
        }

        if (t < Tn - 1) {
            if (tid < 64) {
                const unsigned target = (unsigned)(t + 1);
                const int idx = tid & 31;
                for (;;) {
                    unsigned v = __hip_atomic_load(&tagbase[idx * 16],
                                                   __ATOMIC_RELAXED,
                                                   __HIP_MEMORY_SCOPE_AGENT);
                    if (__ballot(v < target) == 0ull) break;
                    __builtin_amdgcn_s_sleep(1);
                }
            }
            __syncthreads();
        }
    }
#undef D4
}

// ---------------------------------------------------------------------------
extern "C" void kernel_launch(void* const* d_in, const int* in_sizes, int n_in,
                              void* d_out, int out_size, void* d_ws, size_t ws_size,
                              hipStream_t stream) {
    const float* x    = (const float*)d_in[0];
    const float* x2h  = (const float*)d_in[1];
    const float* h2h  = (const float*)d_in[2];
    const float* gam  = (const float*)d_in[3];
    const float* eps  = (const float*)d_in[4];
    const float* bias = (const float*)d_in[5];
    float* out = (float*)d_out;
    float* pre = out + 2 * BTH;      // park pre in the u output slot

    init_tag<<<1, 512, 0, stream>>>();
    pre_gemm<<<dim3(16, 256), dim3(256), 0, stream>>>(x, x2h, bias, pre);

    const unsigned smem2 = (2 * 1028 + 8 * 1028) * sizeof(float);   // 41120 B
    const unsigned smem4 = (4 * 1028 + 32 * 1028) * sizeof(float);  // 148032 B
    (void)hipFuncSetAttribute((const void*)ron_loop2,
                              hipFuncAttributeMaxDynamicSharedMemorySize,
                              (int)smem2);
    (void)hipFuncSetAttribute((const void*)ron_loop4,
                              hipFuncAttributeMaxDynamicSharedMemorySize,
                              (int)smem4);

    void* args[] = {(void*)&h2h, (void*)&gam, (void*)&eps, (void*)&out};

    int maxb = 0;
    hipError_t qe = hipOccupancyMaxActiveBlocksPerMultiprocessor(
        &maxb, (const void*)ron_loop2, 256, (size_t)smem2);

    bool launched = false;
    if (qe == hipSuccess && maxb >= 2) {
        launched = (hipLaunchCooperativeKernel((void*)ron_loop2, dim3(512),
                                               dim3(256), args, smem2,
                                               stream) == hipSuccess);
    }
    if (!launched) {
        (void)hipLaunchCooperativeKernel((void*)ron_loop4, dim3(256),
                                         dim3(256), args, smem4, stream);
    }
}